// Round 14
// baseline (331.461 us; speedup 1.0000x reference)
//
#include <hip/hip_runtime.h>
#include <hip/hip_bf16.h>

#define SEQ   2048
#define DIMSZ 2048
#define NHEAD 16
#define HD    128
#define KDIM  2048

typedef __attribute__((ext_vector_type(8))) short bf16x8;
typedef __attribute__((ext_vector_type(4))) float f32x4;
typedef __attribute__((ext_vector_type(4))) short short4v;
typedef __attribute__((ext_vector_type(4))) float float4v;

__device__ __forceinline__ short f2bf(float f) {
    union { __hip_bfloat16 h; short s; } u;
    u.h = __float2bfloat16(f);
    return u.s;
}

__device__ __forceinline__ unsigned pack_bf2(float lo, float hi) {
    return (unsigned)(unsigned short)f2bf(lo) | ((unsigned)(unsigned short)f2bf(hi) << 16);
}

__device__ __forceinline__ void gload_lds16(const void* g, void* l) {
    __builtin_amdgcn_global_load_lds(
        (const __attribute__((address_space(1))) void*)g,
        (__attribute__((address_space(3))) void*)l, 16, 0, 0);
}

// ---------------- fused prep: x cvt + W_qkv transpose + W_out transpose ----------------
__global__ __launch_bounds__(256) void fused_prep(const float* __restrict__ x,
                                                  short* __restrict__ x_bf,
                                                  const float* __restrict__ W_qkv,
                                                  short* __restrict__ wqkv_t,
                                                  const float* __restrict__ W_out,
                                                  short* __restrict__ wout_t) {
    __shared__ float tile[32][33];
    const int bid = blockIdx.x, tid = threadIdx.x;
    if (bid < 8192) {
        int i = (bid * 256 + tid) * 4;
        float4v v = *reinterpret_cast<const float4v*>(x + i);
        short4v o;
        o[0] = f2bf(v[0]); o[1] = f2bf(v[1]); o[2] = f2bf(v[2]); o[3] = f2bf(v[3]);
        *reinterpret_cast<short4v*>(x_bf + i) = o;
        return;
    }
    const float* in;
    short* out;
    int R, C, c0, r0;
    if (bid < 20480) {
        int tb = bid - 8192;
        in = W_qkv; out = wqkv_t; R = 2048; C = 6144;
        c0 = (tb % 192) * 32; r0 = (tb / 192) * 32;
    } else {
        int tb = bid - 20480;
        in = W_out; out = wout_t; R = 2048; C = 2048;
        c0 = (tb % 64) * 32; r0 = (tb / 64) * 32;
    }
    const int tx = tid & 31, ty = tid >> 5;   // 32 x 8
#pragma unroll
    for (int i = 0; i < 32; i += 8)
        tile[ty + i][tx] = in[(long)(r0 + ty + i) * C + c0 + tx];
    __syncthreads();
#pragma unroll
    for (int i = 0; i < 32; i += 8)
        out[(long)(c0 + ty + i) * R + r0 + tx] = f2bf(tile[tx][ty + i]);
}

// ================= pipelined 4-phase-per-K-tile bf16 GEMM (R8 best: 137.5us) ==========
template <int MODE, int BM, int BN, int WMC, int WNC>
__global__ __launch_bounds__(512, 2) void gemm8p(const short* __restrict__ A,
                                                 const short* __restrict__ Bt,
                                                 const float* __restrict__ bias,
                                                 float* __restrict__ outf,
                                                 short* __restrict__ q_buf,
                                                 short* __restrict__ k_buf,
                                                 short* __restrict__ vt_buf,
                                                 int ntx) {
    constexpr int QMW = (BM / 2) / WMC;
    constexpr int QNW = (BN / 2) / WNC;
    constexpr int MA = QMW / 16;
    constexpr int NB = QNW / 16;
    constexpr int UA = BM / 64, UB = BN / 64, UT = UA + UB;
    constexpr int RA = MA * 2, RB = NB * 2;
    constexpr int BH0C = (BN / 2 + 63) / 64;
    constexpr int NE = UA / 2 + BH0C, NL = UT - NE;
    constexpr int S0 = 2, S2 = 2;
    constexpr int VM0 = NE + S0;
    constexpr int VM2 = NL + S2;
    constexpr int VM3 = (NE - S2) + NE;
    constexpr int NT = KDIM / 64;

    __shared__ __align__(16) short Alds[2][BM * 64];
    __shared__ __align__(16) short Blds[2][BN * 64];

    const int tid = threadIdx.x;
    const int wv = tid >> 6, ln = tid & 63;
    const int lr = ln & 15, lg = ln >> 4;
    const int wm = wv / WNC, wn = wv % WNC;
    const int q8 = gridDim.x >> 3;
    const int id = blockIdx.x;
    const int swz = (id & 7) * q8 + (id >> 3);
    const int m0 = (swz / ntx) * BM, n0 = (swz % ntx) * BN;

    const int r_l = wv * 8 + (ln >> 3);
    const int g8 = ((ln & 7) ^ ((ln >> 3) & 7)) << 3;

#define STAGE_U(u, bufi, TT)                                                   \
    {                                                                          \
        const bool isA_ = (u) < UA / 2 || (u) >= UA / 2 + UB;                  \
        const int idx_ = (u) < UA / 2 ? (u)                                    \
                         : ((u) < UA / 2 + UB ? (u) - UA / 2 : (u) - UB);      \
        if (isA_)                                                              \
            gload_lds16(A + (long)(m0 + idx_ * 64 + r_l) * KDIM + (TT)*64 + g8,\
                        &Alds[bufi][idx_ * 4096 + wv * 512]);                  \
        else                                                                   \
            gload_lds16(Bt + (long)(n0 + idx_ * 64 + r_l) * KDIM + (TT)*64 + g8,\
                        &Blds[bufi][idx_ * 4096 + wv * 512]);                  \
    }

#define RD(L_, row_, kk_) \
    (*reinterpret_cast<const bf16x8*>(&(L_)[(row_)*64 + ((((kk_)*4 + lg) ^ ((row_)&7)) << 3)]))

#define RD_A(bufi, mh, bank)                                                   \
    _Pragma("unroll") for (int mi = 0; mi < MA; ++mi) {                        \
        int r_ = (mh) * (BM / 2) + wm * QMW + mi * 16 + lr;                    \
        bank[mi][0] = RD(Alds[bufi], r_, 0);                                   \
        bank[mi][1] = RD(Alds[bufi], r_, 1);                                   \
    }
#define RD_B(bufi, nh, bank)                                                   \
    _Pragma("unroll") for (int ni = 0; ni < NB; ++ni) {                        \
        int r_ = (nh) * (BN / 2) + wn * QNW + ni * 16 + lr;                    \
        bank[ni][0] = RD(Blds[bufi], r_, 0);                                   \
        bank[ni][1] = RD(Blds[bufi], r_, 1);                                   \
    }

#define MFMA_Q(qi, AB, BB)                                                     \
    __builtin_amdgcn_s_setprio(1);                                             \
    _Pragma("unroll") for (int kk = 0; kk < 2; ++kk)                           \
        _Pragma("unroll") for (int mi = 0; mi < MA; ++mi)                      \
            _Pragma("unroll") for (int ni = 0; ni < NB; ++ni)                  \
                acc[qi][mi][ni] = __builtin_amdgcn_mfma_f32_16x16x32_bf16(     \
                    AB[mi][kk], BB[ni][kk], acc[qi][mi][ni], 0, 0, 0);         \
    __builtin_amdgcn_s_setprio(0);

#define LGKM(n)                                                                \
    asm volatile("s_waitcnt lgkmcnt(%0)" ::"i"(n) : "memory");                 \
    __builtin_amdgcn_sched_barrier(0);
#define VMC(n) asm volatile("s_waitcnt vmcnt(%0)" ::"i"(n) : "memory");
#define BAR()                                                                  \
    __builtin_amdgcn_s_barrier();                                              \
    __builtin_amdgcn_sched_barrier(0);

    f32x4 acc[4][MA][NB] = {};
    bf16x8 aF0[MA][2], aF1[MA][2], bF0a[NB][2], bF0b[NB][2], bF1[NB][2];

#pragma unroll
    for (int u = 0; u < UT; ++u) STAGE_U(u, 0, 0);
#pragma unroll
    for (int u = 0; u < NE; ++u) STAGE_U(u, 1, 1);
    VMC(NE);
    BAR();
    RD_A(0, 0, aF0);
    RD_B(0, 0, bF0a);

#define TILE_BODY(PAR, T_, BF0C, BF0N)                                         \
    {                                                                          \
        constexpr int cur = PAR, nxt = PAR ^ 1;                                \
        RD_B(cur, 1, bF1);                                                     \
        if ((T_) + 1 < NT) {                                                   \
            STAGE_U(NE + 0, nxt, (T_) + 1);                                    \
            STAGE_U(NE + 1, nxt, (T_) + 1);                                    \
        }                                                                      \
        LGKM(RB);                                                              \
        MFMA_Q(0, aF0, BF0C);                                                  \
        VMC(VM0);                                                              \
        BAR();                                                                 \
        RD_A(cur, 1, aF1);                                                     \
        if ((T_) + 1 < NT) {                                                   \
            _Pragma("unroll") for (int u = NE + S0; u < UT; ++u)               \
                STAGE_U(u, nxt, (T_) + 1);                                     \
        }                                                                      \
        LGKM(RA);                                                              \
        MFMA_Q(1, aF0, bF1);                                                   \
        BAR();                                                                 \
        if ((T_) + 2 < NT) {                                                   \
            STAGE_U(0, cur, (T_) + 2);                                         \
            STAGE_U(1, cur, (T_) + 2);                                         \
        }                                                                      \
        LGKM(0);                                                               \
        MFMA_Q(2, aF1, bF1);                                                   \
        if ((T_) + 2 < NT) { VMC(VM2); } else { VMC(NL); }                     \
        BAR();                                                                 \
        if ((T_) + 1 < NT) {                                                   \
            RD_A(nxt, 0, aF0);                                                 \
            RD_B(nxt, 0, BF0N);                                                \
        }                                                                      \
        if ((T_) + 2 < NT) {                                                   \
            _Pragma("unroll") for (int u = S2; u < NE; ++u)                    \
                STAGE_U(u, cur, (T_) + 2);                                     \
        }                                                                      \
        LGKM(RA + RB);                                                         \
        MFMA_Q(3, aF1, BF0C);                                                  \
        if ((T_) + 2 < NT) { VMC(VM3); } else { VMC(0); }                      \
        BAR();                                                                 \
    }

    for (int TT = 0; TT < NT; TT += 2) {
        TILE_BODY(0, TT, bF0a, bF0b);
        TILE_BODY(1, TT + 1, bF0b, bF0a);
    }

    const int MH[4] = {0, 0, 1, 1}, NHq[4] = {0, 1, 1, 0};
#pragma unroll
    for (int q = 0; q < 4; ++q) {
#pragma unroll
        for (int mi = 0; mi < MA; ++mi) {
#pragma unroll
            for (int ni = 0; ni < NB; ++ni) {
                int col = n0 + NHq[q] * (BN / 2) + wn * QNW + ni * 16 + lr;
                float bv = bias[col];
#pragma unroll
                for (int j = 0; j < 4; ++j) {
                    int row = m0 + MH[q] * (BM / 2) + wm * QMW + mi * 16 + lg * 4 + j;
                    float v = acc[q][mi][ni][j] + bv;
                    if (MODE == 0) {
                        int h = col / (3 * HD);
                        int jj = col - h * (3 * HD);
                        int b = row >> 11, s = row & 2047;
                        int bh = b * NHEAD + h;
                        short sv = f2bf(v);
                        if (jj < HD)
                            q_buf[(bh * SEQ + s) * HD + jj] = sv;
                        else if (jj < 2 * HD)
                            k_buf[(bh * SEQ + s) * HD + (jj - HD)] = sv;
                        else
                            vt_buf[(bh * HD + (jj - 2 * HD)) * SEQ + s] = sv;
                    } else {
                        outf[(long)row * DIMSZ + col] = v;
                    }
                }
            }
        }
    }
#undef STAGE_U
#undef RD
#undef RD_A
#undef RD_B
#undef MFMA_Q
#undef LGKM
#undef VMC
#undef BAR
#undef TILE_BODY
}

// ---------------- causal flash attention: swapped-QK^T, V single-buffered, 3 blocks/CU --
// LDS 48KB: Klds double (2x16KB) + Vlds single (16KB).  Per tile t:
//   top[bar passed: K(t) published, V(t-1) reads done]: stageV(t)          (RAW: V needed
//   ~1000cyc later at PV; WAR: end-bar of t-1 covers) -> kf+QK^T -> stageK(t+1,cur^1)
//   -> softmax -> vmcnt(4) [V(t) landed, K(t+1) in flight] + bar -> PV(Vlds)
//   -> vmcnt(0) + bar [K(t+1) landed+published].
__global__ __launch_bounds__(256, 3) void attn_kernel(const short* __restrict__ q_buf,
                                                      const short* __restrict__ k_buf,
                                                      const short* __restrict__ vt_buf,
                                                      short* __restrict__ ao) {
    __shared__ __align__(16) short Klds[2][64 * 128];
    __shared__ __align__(16) short Vlds[128 * 64];
    const int tid = threadIdx.x;
    const int wave = tid >> 6, lane = tid & 63;
    const int lr = lane & 15, lg = lane >> 4;
    const int bx = blockIdx.x;
    const int qt = 15 - (bx >> 5);      // heavy q-tiles dispatched first
    const int bh = bx & 31;
    const int b = bh >> 4, h = bh & 15;
    const int qbase = qt * 128 + wave * 32;
    const float c2 = 0.12752775f;       // (1/sqrt(128)) * log2(e)

    bf16x8 qf[2][4];
    {
        const short* qrow = q_buf + ((long)(bh * SEQ + qbase + lr)) * HD;
#pragma unroll
        for (int mi = 0; mi < 2; ++mi)
#pragma unroll
            for (int c = 0; c < 4; ++c)
                qf[mi][c] = *reinterpret_cast<const bf16x8*>(
                    qrow + mi * 16 * HD + c * 32 + lg * 8);
    }
    asm volatile("s_waitcnt vmcnt(0)" ::: "memory");  // drain Q so counts below are exact

    const char* kbase = (const char*)(k_buf + (long)bh * SEQ * HD);
    const char* vbase = (const char*)(vt_buf + (long)bh * HD * SEQ);
    const int krow_l = wave * 4 + (lane >> 4);
    const int kcol_l = ((lane & 15) * 16) ^ ((krow_l & 7) << 4);
    const int vrow_l = wave * 8 + (lane >> 3);
    const int vcol_l = ((lane & 7) * 16) ^ ((vrow_l & 7) << 4);

    const int nt = 2 * (qt + 1);
    auto stageK = [&](int bufi, int t) {
        const char* ks = kbase + (long)t * 16384 + (long)krow_l * 256 + kcol_l;
        short* kd = &Klds[bufi][wave * 512];
#pragma unroll
        for (int i = 0; i < 4; ++i)
            gload_lds16(ks + i * 4096, kd + i * 2048);
    };
    auto stageV = [&](int t) {
        const char* vs = vbase + (long)t * 128 + (long)vrow_l * (SEQ * 2) + vcol_l;
        short* vd = &Vlds[wave * 512];
#pragma unroll
        for (int i = 0; i < 4; ++i)
            gload_lds16(vs + (long)i * 32 * SEQ * 2, vd + i * 2048);
    };

    f32x4 o_acc[2][8] = {};
    float mrow[2] = {-1e30f, -1e30f}, lrow[2] = {0.f, 0.f};  // lrow = per-lane partial

    // PA-shuffle lane constants
    const int s0 = (lane & 15) | ((lane & 16) << 1);  // lr + (lg&1)*32
    const int s1 = s0 + 16;
    const bool hi_ni = (lane & 32) != 0;

    // prologue: K(0) landed + published
    stageK(0, 0);
    asm volatile("s_waitcnt vmcnt(0)" ::: "memory");
    __builtin_amdgcn_s_barrier();
    __builtin_amdgcn_sched_barrier(0);

    for (int t = 0; t < nt; ++t) {
        const int cur = t & 1;
        const int kv0 = t * 64;
        const bool work = kv0 <= qbase + 31;

        stageV(t);                       // own slice of V(t); needed at PV (~1000cyc away)

        f32x4 sc[2][4] = {};
        if (work) {
            const short* kl = &Klds[cur][0];
#pragma unroll
            for (int c = 0; c < 4; ++c) {
                bf16x8 kf[4];
#pragma unroll
                for (int ni = 0; ni < 4; ++ni)
                    kf[ni] = *reinterpret_cast<const bf16x8*>(
                        kl + (((ni * 16 + lr) * 256 +
                               ((c * 64 + lg * 16) ^ ((lr & 7) << 4))) >> 1));
                __builtin_amdgcn_s_setprio(1);
#pragma unroll
                for (int mi = 0; mi < 2; ++mi)
#pragma unroll
                    for (int ni = 0; ni < 4; ++ni)
                        sc[mi][ni] = __builtin_amdgcn_mfma_f32_16x16x32_bf16(
                            kf[ni], qf[mi][c], sc[mi][ni], 0, 0, 0);
                __builtin_amdgcn_s_setprio(0);
            }
        }
        if (t + 1 < nt) stageK(cur ^ 1, t + 1);   // K(t+1); waited at end of this tile

        unsigned pk[2][4][2];
        if (work) {
            // ---- mask + scale (exp2 domain) in place; in-lane row max
            const bool full = (kv0 + 63) <= qbase;
            float mx[2];
#pragma unroll
            for (int mi = 0; mi < 2; ++mi) {
                float m_ = -3e38f;
                const int qg = qbase + mi * 16 + lr;
#pragma unroll
                for (int ni = 0; ni < 4; ++ni)
#pragma unroll
                    for (int j = 0; j < 4; ++j) {
                        float v = sc[mi][ni][j] * c2;
                        if (!full && (kv0 + ni * 16 + lg * 4 + j > qg)) v = -1e9f;
                        sc[mi][ni][j] = v;
                        m_ = fmaxf(m_, v);
                    }
                mx[mi] = m_;
            }
#pragma unroll
            for (int mi = 0; mi < 2; ++mi) {
                mx[mi] = fmaxf(mx[mi], __shfl_xor(mx[mi], 16, 64));
                mx[mi] = fmaxf(mx[mi], __shfl_xor(mx[mi], 32, 64));
            }
            float md = fmaxf(mx[0] - mrow[0], mx[1] - mrow[1]);
            if (!__all(md <= 11.5f)) {
#pragma unroll
                for (int mi = 0; mi < 2; ++mi) {
                    float mn = fmaxf(mrow[mi], mx[mi]);
                    float a = exp2f(mrow[mi] - mn);
                    mrow[mi] = mn;
                    lrow[mi] *= a;
#pragma unroll
                    for (int j = 0; j < 4; ++j) {
                        float aj = __shfl(a, (lane & 48) | (lg * 4 + j), 64);
#pragma unroll
                        for (int n = 0; n < 8; ++n)
                            o_acc[mi][n][j] *= aj;
                    }
                }
            }
#pragma unroll
            for (int mi = 0; mi < 2; ++mi) {
                float ps = 0.f;
#pragma unroll
                for (int ni = 0; ni < 4; ++ni) {
#pragma unroll
                    for (int j = 0; j < 4; ++j) {
                        float p = exp2f(sc[mi][ni][j] - mrow[mi]);
                        sc[mi][ni][j] = p;
                        ps += p;
                    }
                    pk[mi][ni][0] = pack_bf2(sc[mi][ni][0], sc[mi][ni][1]);
                    pk[mi][ni][1] = pack_bf2(sc[mi][ni][2], sc[mi][ni][3]);
                }
                lrow[mi] += ps;
            }
        }

        // V(t) landed (4 oldest of the ≤8 outstanding); K(t+1) may stay in flight
        if (t + 1 < nt) {
            asm volatile("s_waitcnt vmcnt(4)" ::: "memory");
        } else {
            asm volatile("s_waitcnt vmcnt(0)" ::: "memory");
        }
        __builtin_amdgcn_s_barrier();            // publish V(t)
        __builtin_amdgcn_sched_barrier(0);

        if (work) {
            const short* vl = &Vlds[0];
#pragma unroll
            for (int kc = 0; kc < 2; ++kc) {
                union { int i[4]; bf16x8 v; } pa[2];
#pragma unroll
                for (int mi = 0; mi < 2; ++mi) {
                    int a0 = __shfl((int)pk[mi][2 * kc][0], s0, 64);
                    int b0 = __shfl((int)pk[mi][2 * kc + 1][0], s0, 64);
                    int a1 = __shfl((int)pk[mi][2 * kc][1], s0, 64);
                    int b1 = __shfl((int)pk[mi][2 * kc + 1][1], s0, 64);
                    int a2 = __shfl((int)pk[mi][2 * kc][0], s1, 64);
                    int b2 = __shfl((int)pk[mi][2 * kc + 1][0], s1, 64);
                    int a3 = __shfl((int)pk[mi][2 * kc][1], s1, 64);
                    int b3 = __shfl((int)pk[mi][2 * kc + 1][1], s1, 64);
                    pa[mi].i[0] = hi_ni ? b0 : a0;
                    pa[mi].i[1] = hi_ni ? b1 : a1;
                    pa[mi].i[2] = hi_ni ? b2 : a2;
                    pa[mi].i[3] = hi_ni ? b3 : a3;
                }
#pragma unroll
                for (int n = 0; n < 8; ++n) {
                    bf16x8 vf = *reinterpret_cast<const bf16x8*>(
                        vl + (((n * 16 + lr) * 128 +
                               ((kc * 64 + lg * 16) ^ ((lr & 7) << 4))) >> 1));
                    __builtin_amdgcn_s_setprio(1);
#pragma unroll
                    for (int mi = 0; mi < 2; ++mi)
                        o_acc[mi][n] = __builtin_amdgcn_mfma_f32_16x16x32_bf16(
                            pa[mi].v, vf, o_acc[mi][n], 0, 0, 0);
                    __builtin_amdgcn_s_setprio(0);
                }
            }
        }

        // K(t+1) landed; all waves done with Vlds reads (MFMA lgkm waits precede)
        asm volatile("s_waitcnt vmcnt(0)" ::: "memory");
        __builtin_amdgcn_s_barrier();
        __builtin_amdgcn_sched_barrier(0);
    }

    // ---- epilogue: reduce lrow partials, normalize, store
    float invq[2];
#pragma unroll
    for (int mi = 0; mi < 2; ++mi) {
        float s = lrow[mi];
        s += __shfl_xor(s, 16, 64);
        s += __shfl_xor(s, 32, 64);
        invq[mi] = 1.0f / s;
    }
    short* aor = ao + ((long)(b * SEQ + qbase) * DIMSZ + h * HD);
#pragma unroll
    for (int mi = 0; mi < 2; ++mi)
#pragma unroll
        for (int j = 0; j < 4; ++j) {
            float ij = __shfl(invq[mi], (lane & 48) | (lg * 4 + j), 64);
#pragma unroll
            for (int n = 0; n < 8; ++n)
                aor[(mi * 16 + lg * 4 + j) * DIMSZ + n * 16 + lr] =
                    f2bf(o_acc[mi][n][j] * ij);
        }
}

// ---------------- launcher ----------------
extern "C" void kernel_launch(void* const* d_in, const int* in_sizes, int n_in,
                              void* d_out, int out_size, void* d_ws, size_t ws_size,
                              hipStream_t stream) {
    const float* x     = (const float*)d_in[0];
    // d_in[1] is the causal mask; semantics hardcoded (tril), not read.
    const float* W_qkv = (const float*)d_in[2];
    const float* b_qkv = (const float*)d_in[3];
    const float* W_out = (const float*)d_in[4];
    const float* b_out = (const float*)d_in[5];
    float* out = (float*)d_out;

    char* ws = (char*)d_ws;
    short* x_bf   = (short*)ws;                          // 16 MB
    short* wqkv_t = (short*)(ws + (size_t)16 * 1048576); // 24 MB
    short* wout_t = (short*)(ws + (size_t)40 * 1048576); //  8 MB
    short* q_buf  = (short*)(ws + (size_t)48 * 1048576); // 16 MB
    short* k_buf  = (short*)(ws + (size_t)64 * 1048576); // 16 MB
    short* vt_buf = (short*)(ws + (size_t)80 * 1048576); // 16 MB
    short* ao     = x_bf;  // x_bf dead after gemm1; reuse for attention output

    fused_prep<<<24576, 256, 0, stream>>>(x, x_bf, W_qkv, wqkv_t, W_out, wout_t);
    // gemm1: 4096x6144x2048, tiles 256x192 -> 16x32 = 512 blocks (2 full rounds)
    gemm8p<0, 256, 192, 4, 2><<<512, 512, 0, stream>>>(x_bf, wqkv_t, b_qkv, nullptr,
                                                       q_buf, k_buf, vt_buf, 32);
    attn_kernel<<<512, 256, 0, stream>>>(q_buf, k_buf, vt_buf, ao);
    // gemm2: 4096x2048x2048, tiles 128x256 -> 32x8 = 256 blocks (1 round)
    gemm8p<1, 128, 256, 2, 4><<<256, 512, 0, stream>>>(ao, wout_t, b_out, out,
                                                       nullptr, nullptr, nullptr, 8);
}

// Round 15
// 286.518 us; speedup vs baseline: 1.1569x; 1.1569x over previous
//
#include <hip/hip_runtime.h>
#include <hip/hip_bf16.h>

#define SEQ   2048
#define DIMSZ 2048
#define NHEAD 16
#define HD    128
#define KDIM  2048

typedef __attribute__((ext_vector_type(8))) short bf16x8;
typedef __attribute__((ext_vector_type(4))) float f32x4;
typedef __attribute__((ext_vector_type(4))) short short4v;
typedef __attribute__((ext_vector_type(4))) float float4v;

__device__ __forceinline__ short f2bf(float f) {
    union { __hip_bfloat16 h; short s; } u;
    u.h = __float2bfloat16(f);
    return u.s;
}

__device__ __forceinline__ unsigned pack_bf2(float lo, float hi) {
    return (unsigned)(unsigned short)f2bf(lo) | ((unsigned)(unsigned short)f2bf(hi) << 16);
}

__device__ __forceinline__ void gload_lds16(const void* g, void* l) {
    __builtin_amdgcn_global_load_lds(
        (const __attribute__((address_space(1))) void*)g,
        (__attribute__((address_space(3))) void*)l, 16, 0, 0);
}

// ---------------- fused prep: x cvt + W_qkv transpose + W_out transpose ----------------
__global__ __launch_bounds__(256) void fused_prep(const float* __restrict__ x,
                                                  short* __restrict__ x_bf,
                                                  const float* __restrict__ W_qkv,
                                                  short* __restrict__ wqkv_t,
                                                  const float* __restrict__ W_out,
                                                  short* __restrict__ wout_t) {
    __shared__ float tile[32][33];
    const int bid = blockIdx.x, tid = threadIdx.x;
    if (bid < 8192) {
        int i = (bid * 256 + tid) * 4;
        float4v v = *reinterpret_cast<const float4v*>(x + i);
        short4v o;
        o[0] = f2bf(v[0]); o[1] = f2bf(v[1]); o[2] = f2bf(v[2]); o[3] = f2bf(v[3]);
        *reinterpret_cast<short4v*>(x_bf + i) = o;
        return;
    }
    const float* in;
    short* out;
    int R, C, c0, r0;
    if (bid < 20480) {
        int tb = bid - 8192;
        in = W_qkv; out = wqkv_t; R = 2048; C = 6144;
        c0 = (tb % 192) * 32; r0 = (tb / 192) * 32;
    } else {
        int tb = bid - 20480;
        in = W_out; out = wout_t; R = 2048; C = 2048;
        c0 = (tb % 64) * 32; r0 = (tb / 64) * 32;
    }
    const int tx = tid & 31, ty = tid >> 5;   // 32 x 8
#pragma unroll
    for (int i = 0; i < 32; i += 8)
        tile[ty + i][tx] = in[(long)(r0 + ty + i) * C + c0 + tx];
    __syncthreads();
#pragma unroll
    for (int i = 0; i < 32; i += 8)
        out[(long)(c0 + ty + i) * R + r0 + tx] = f2bf(tile[tx][ty + i]);
}

// ================= pipelined 4-phase-per-K-tile bf16 GEMM (R8 best: 137.5us) ==========
template <int MODE, int BM, int BN, int WMC, int WNC>
__global__ __launch_bounds__(512, 2) void gemm8p(const short* __restrict__ A,
                                                 const short* __restrict__ Bt,
                                                 const float* __restrict__ bias,
                                                 float* __restrict__ outf,
                                                 short* __restrict__ q_buf,
                                                 short* __restrict__ k_buf,
                                                 short* __restrict__ vt_buf,
                                                 int ntx) {
    constexpr int QMW = (BM / 2) / WMC;
    constexpr int QNW = (BN / 2) / WNC;
    constexpr int MA = QMW / 16;
    constexpr int NB = QNW / 16;
    constexpr int UA = BM / 64, UB = BN / 64, UT = UA + UB;
    constexpr int RA = MA * 2, RB = NB * 2;
    constexpr int BH0C = (BN / 2 + 63) / 64;
    constexpr int NE = UA / 2 + BH0C, NL = UT - NE;
    constexpr int S0 = 2, S2 = 2;
    constexpr int VM0 = NE + S0;
    constexpr int VM2 = NL + S2;
    constexpr int VM3 = (NE - S2) + NE;
    constexpr int NT = KDIM / 64;

    __shared__ __align__(16) short Alds[2][BM * 64];
    __shared__ __align__(16) short Blds[2][BN * 64];

    const int tid = threadIdx.x;
    const int wv = tid >> 6, ln = tid & 63;
    const int lr = ln & 15, lg = ln >> 4;
    const int wm = wv / WNC, wn = wv % WNC;
    const int q8 = gridDim.x >> 3;
    const int id = blockIdx.x;
    const int swz = (id & 7) * q8 + (id >> 3);
    const int m0 = (swz / ntx) * BM, n0 = (swz % ntx) * BN;

    const int r_l = wv * 8 + (ln >> 3);
    const int g8 = ((ln & 7) ^ ((ln >> 3) & 7)) << 3;

#define STAGE_U(u, bufi, TT)                                                   \
    {                                                                          \
        const bool isA_ = (u) < UA / 2 || (u) >= UA / 2 + UB;                  \
        const int idx_ = (u) < UA / 2 ? (u)                                    \
                         : ((u) < UA / 2 + UB ? (u) - UA / 2 : (u) - UB);      \
        if (isA_)                                                              \
            gload_lds16(A + (long)(m0 + idx_ * 64 + r_l) * KDIM + (TT)*64 + g8,\
                        &Alds[bufi][idx_ * 4096 + wv * 512]);                  \
        else                                                                   \
            gload_lds16(Bt + (long)(n0 + idx_ * 64 + r_l) * KDIM + (TT)*64 + g8,\
                        &Blds[bufi][idx_ * 4096 + wv * 512]);                  \
    }

#define RD(L_, row_, kk_) \
    (*reinterpret_cast<const bf16x8*>(&(L_)[(row_)*64 + ((((kk_)*4 + lg) ^ ((row_)&7)) << 3)]))

#define RD_A(bufi, mh, bank)                                                   \
    _Pragma("unroll") for (int mi = 0; mi < MA; ++mi) {                        \
        int r_ = (mh) * (BM / 2) + wm * QMW + mi * 16 + lr;                    \
        bank[mi][0] = RD(Alds[bufi], r_, 0);                                   \
        bank[mi][1] = RD(Alds[bufi], r_, 1);                                   \
    }
#define RD_B(bufi, nh, bank)                                                   \
    _Pragma("unroll") for (int ni = 0; ni < NB; ++ni) {                        \
        int r_ = (nh) * (BN / 2) + wn * QNW + ni * 16 + lr;                    \
        bank[ni][0] = RD(Blds[bufi], r_, 0);                                   \
        bank[ni][1] = RD(Blds[bufi], r_, 1);                                   \
    }

#define MFMA_Q(qi, AB, BB)                                                     \
    __builtin_amdgcn_s_setprio(1);                                             \
    _Pragma("unroll") for (int kk = 0; kk < 2; ++kk)                           \
        _Pragma("unroll") for (int mi = 0; mi < MA; ++mi)                      \
            _Pragma("unroll") for (int ni = 0; ni < NB; ++ni)                  \
                acc[qi][mi][ni] = __builtin_amdgcn_mfma_f32_16x16x32_bf16(     \
                    AB[mi][kk], BB[ni][kk], acc[qi][mi][ni], 0, 0, 0);         \
    __builtin_amdgcn_s_setprio(0);

#define LGKM(n)                                                                \
    asm volatile("s_waitcnt lgkmcnt(%0)" ::"i"(n) : "memory");                 \
    __builtin_amdgcn_sched_barrier(0);
#define VMC(n) asm volatile("s_waitcnt vmcnt(%0)" ::"i"(n) : "memory");
#define BAR()                                                                  \
    __builtin_amdgcn_s_barrier();                                              \
    __builtin_amdgcn_sched_barrier(0);

    f32x4 acc[4][MA][NB] = {};
    bf16x8 aF0[MA][2], aF1[MA][2], bF0a[NB][2], bF0b[NB][2], bF1[NB][2];

#pragma unroll
    for (int u = 0; u < UT; ++u) STAGE_U(u, 0, 0);
#pragma unroll
    for (int u = 0; u < NE; ++u) STAGE_U(u, 1, 1);
    VMC(NE);
    BAR();
    RD_A(0, 0, aF0);
    RD_B(0, 0, bF0a);

#define TILE_BODY(PAR, T_, BF0C, BF0N)                                         \
    {                                                                          \
        constexpr int cur = PAR, nxt = PAR ^ 1;                                \
        RD_B(cur, 1, bF1);                                                     \
        if ((T_) + 1 < NT) {                                                   \
            STAGE_U(NE + 0, nxt, (T_) + 1);                                    \
            STAGE_U(NE + 1, nxt, (T_) + 1);                                    \
        }                                                                      \
        LGKM(RB);                                                              \
        MFMA_Q(0, aF0, BF0C);                                                  \
        VMC(VM0);                                                              \
        BAR();                                                                 \
        RD_A(cur, 1, aF1);                                                     \
        if ((T_) + 1 < NT) {                                                   \
            _Pragma("unroll") for (int u = NE + S0; u < UT; ++u)               \
                STAGE_U(u, nxt, (T_) + 1);                                     \
        }                                                                      \
        LGKM(RA);                                                              \
        MFMA_Q(1, aF0, bF1);                                                   \
        BAR();                                                                 \
        if ((T_) + 2 < NT) {                                                   \
            STAGE_U(0, cur, (T_) + 2);                                         \
            STAGE_U(1, cur, (T_) + 2);                                         \
        }                                                                      \
        LGKM(0);                                                               \
        MFMA_Q(2, aF1, bF1);                                                   \
        if ((T_) + 2 < NT) { VMC(VM2); } else { VMC(NL); }                     \
        BAR();                                                                 \
        if ((T_) + 1 < NT) {                                                   \
            RD_A(nxt, 0, aF0);                                                 \
            RD_B(nxt, 0, BF0N);                                                \
        }                                                                      \
        if ((T_) + 2 < NT) {                                                   \
            _Pragma("unroll") for (int u = S2; u < NE; ++u)                    \
                STAGE_U(u, cur, (T_) + 2);                                     \
        }                                                                      \
        LGKM(RA + RB);                                                         \
        MFMA_Q(3, aF1, BF0C);                                                  \
        if ((T_) + 2 < NT) { VMC(VM3); } else { VMC(0); }                      \
        BAR();                                                                 \
    }

    for (int TT = 0; TT < NT; TT += 2) {
        TILE_BODY(0, TT, bF0a, bF0b);
        TILE_BODY(1, TT + 1, bF0b, bF0a);
    }

    const int MH[4] = {0, 0, 1, 1}, NHq[4] = {0, 1, 1, 0};
#pragma unroll
    for (int q = 0; q < 4; ++q) {
#pragma unroll
        for (int mi = 0; mi < MA; ++mi) {
#pragma unroll
            for (int ni = 0; ni < NB; ++ni) {
                int col = n0 + NHq[q] * (BN / 2) + wn * QNW + ni * 16 + lr;
                float bv = bias[col];
#pragma unroll
                for (int j = 0; j < 4; ++j) {
                    int row = m0 + MH[q] * (BM / 2) + wm * QMW + mi * 16 + lg * 4 + j;
                    float v = acc[q][mi][ni][j] + bv;
                    if (MODE == 0) {
                        int h = col / (3 * HD);
                        int jj = col - h * (3 * HD);
                        int b = row >> 11, s = row & 2047;
                        int bh = b * NHEAD + h;
                        short sv = f2bf(v);
                        if (jj < HD)
                            q_buf[(bh * SEQ + s) * HD + jj] = sv;
                        else if (jj < 2 * HD)
                            k_buf[(bh * SEQ + s) * HD + (jj - HD)] = sv;
                        else
                            vt_buf[(bh * HD + (jj - 2 * HD)) * SEQ + s] = sv;
                    } else {
                        outf[(long)row * DIMSZ + col] = v;
                    }
                }
            }
        }
    }
#undef STAGE_U
#undef RD
#undef RD_A
#undef RD_B
#undef MFMA_Q
#undef LGKM
#undef VMC
#undef BAR
#undef TILE_BODY
}

// ---------------- causal flash attention (R13-verified skeleton, balanced qt pairing) ----
// qt mapping: g = bx>>5; qt = g<8 ? 15-g : g-8.  With round-robin block->CU placement,
// CU c hosts blocks {c, c+256} whose tile counts sum to 34 for ALL c (was 20..48 skew).
__global__ __launch_bounds__(256, 2) void attn_kernel(const short* __restrict__ q_buf,
                                                      const short* __restrict__ k_buf,
                                                      const short* __restrict__ vt_buf,
                                                      short* __restrict__ ao) {
    __shared__ __align__(16) short Klds[2][64 * 128];
    __shared__ __align__(16) short Vlds[2][128 * 64];
    const int tid = threadIdx.x;
    const int wave = tid >> 6, lane = tid & 63;
    const int lr = lane & 15, lg = lane >> 4;
    const int bx = blockIdx.x;
    const int g = bx >> 5;
    const int qt = (g < 8) ? (15 - g) : (g - 8);   // balanced heavy/light pairing
    const int bh = bx & 31;
    const int b = bh >> 4, h = bh & 15;
    const int qbase = qt * 128 + wave * 32;
    const float c2 = 0.12752775f;       // (1/sqrt(128)) * log2(e)

    bf16x8 qf[2][4];
    {
        const short* qrow = q_buf + ((long)(bh * SEQ + qbase + lr)) * HD;
#pragma unroll
        for (int mi = 0; mi < 2; ++mi)
#pragma unroll
            for (int c = 0; c < 4; ++c)
                qf[mi][c] = *reinterpret_cast<const bf16x8*>(
                    qrow + mi * 16 * HD + c * 32 + lg * 8);
    }
    asm volatile("s_waitcnt vmcnt(0)" ::: "memory");  // drain Q so vmcnt(8) below is exact

    const char* kbase = (const char*)(k_buf + (long)bh * SEQ * HD);
    const char* vbase = (const char*)(vt_buf + (long)bh * HD * SEQ);
    const int krow_l = wave * 4 + (lane >> 4);
    const int kcol_l = ((lane & 15) * 16) ^ ((krow_l & 7) << 4);
    const int vrow_l = wave * 8 + (lane >> 3);
    const int vcol_l = ((lane & 7) * 16) ^ ((vrow_l & 7) << 4);

    const int nt = 2 * (qt + 1);
    auto stage = [&](int bufi, int t) {
        const char* ks = kbase + (long)t * 16384 + (long)krow_l * 256 + kcol_l;
        const char* vs = vbase + (long)t * 128 + (long)vrow_l * (SEQ * 2) + vcol_l;
        short* kd = &Klds[bufi][wave * 512];
        short* vd = &Vlds[bufi][wave * 512];
#pragma unroll
        for (int i = 0; i < 4; ++i) {
            gload_lds16(ks + i * 4096, kd + i * 2048);
            gload_lds16(vs + (long)i * 32 * SEQ * 2, vd + i * 2048);
        }
    };

    f32x4 o_acc[2][8] = {};
    float mrow[2] = {-1e30f, -1e30f}, lrow[2] = {0.f, 0.f};  // lrow = per-lane partial

    // PA-shuffle lane constants
    const int s0 = (lane & 15) | ((lane & 16) << 1);  // lr + (lg&1)*32
    const int s1 = s0 + 16;
    const bool hi_ni = (lane & 32) != 0;

    stage(0, 0);
    for (int t = 0; t < nt; ++t) {
        const int cur = t & 1;
        if (t + 1 < nt) {
            stage(cur ^ 1, t + 1);
            asm volatile("s_waitcnt vmcnt(8)" ::: "memory");
        } else {
            asm volatile("s_waitcnt vmcnt(0)" ::: "memory");
        }
        __builtin_amdgcn_s_barrier();
        __builtin_amdgcn_sched_barrier(0);

        const int kv0 = t * 64;
        if (kv0 <= qbase + 31) {
            const short* kl = &Klds[cur][0];
            const short* vl = &Vlds[cur][0];
            // ---- hoisted K-fragment reads
            bf16x8 kf[4][4];
#pragma unroll
            for (int c = 0; c < 4; ++c)
#pragma unroll
                for (int ni = 0; ni < 4; ++ni)
                    kf[c][ni] = *reinterpret_cast<const bf16x8*>(
                        kl + (((ni * 16 + lr) * 256 +
                               ((c * 64 + lg * 16) ^ ((lr & 7) << 4))) >> 1));
            // ---- QK^T (swapped): sc[mi][ni][j] = S[q=qbase+mi*16+lr][k=kv0+ni*16+lg*4+j]
            f32x4 sc[2][4] = {};
            __builtin_amdgcn_s_setprio(1);
#pragma unroll
            for (int c = 0; c < 4; ++c)
#pragma unroll
                for (int mi = 0; mi < 2; ++mi)
#pragma unroll
                    for (int ni = 0; ni < 4; ++ni)
                        sc[mi][ni] = __builtin_amdgcn_mfma_f32_16x16x32_bf16(
                            kf[c][ni], qf[mi][c], sc[mi][ni], 0, 0, 0);
            __builtin_amdgcn_s_setprio(0);
            // ---- EARLY V prefetch: latency hides under softmax
            bf16x8 vfr[2][8];
#pragma unroll
            for (int kc = 0; kc < 2; ++kc)
#pragma unroll
                for (int n = 0; n < 8; ++n)
                    vfr[kc][n] = *reinterpret_cast<const bf16x8*>(
                        vl + (((n * 16 + lr) * 128 +
                               ((kc * 64 + lg * 16) ^ ((lr & 7) << 4))) >> 1));
            // ---- mask + scale (exp2 domain) in place; in-lane row max
            const bool full = (kv0 + 63) <= qbase;
            float mx[2];
#pragma unroll
            for (int mi = 0; mi < 2; ++mi) {
                float m_ = -3e38f;
                const int qg = qbase + mi * 16 + lr;
#pragma unroll
                for (int ni = 0; ni < 4; ++ni)
#pragma unroll
                    for (int j = 0; j < 4; ++j) {
                        float v = sc[mi][ni][j] * c2;
                        if (!full && (kv0 + ni * 16 + lg * 4 + j > qg)) v = -1e9f;
                        sc[mi][ni][j] = v;
                        m_ = fmaxf(m_, v);
                    }
                mx[mi] = m_;
            }
#pragma unroll
            for (int mi = 0; mi < 2; ++mi) {
                mx[mi] = fmaxf(mx[mi], __shfl_xor(mx[mi], 16, 64));
                mx[mi] = fmaxf(mx[mi], __shfl_xor(mx[mi], 32, 64));
            }
            // ---- defer-max rescale (wave-uniform skip)
            float md = fmaxf(mx[0] - mrow[0], mx[1] - mrow[1]);
            if (!__all(md <= 11.5f)) {
#pragma unroll
                for (int mi = 0; mi < 2; ++mi) {
                    float mn = fmaxf(mrow[mi], mx[mi]);
                    float a = exp2f(mrow[mi] - mn);
                    mrow[mi] = mn;
                    lrow[mi] *= a;
#pragma unroll
                    for (int j = 0; j < 4; ++j) {
                        float aj = __shfl(a, (lane & 48) | (lg * 4 + j), 64);
#pragma unroll
                        for (int n = 0; n < 8; ++n)
                            o_acc[mi][n][j] *= aj;
                    }
                }
            }
            // ---- P = exp2(S - m) in place; per-lane partial row sum; pack bf16
            unsigned pk[2][4][2];
#pragma unroll
            for (int mi = 0; mi < 2; ++mi) {
                float ps = 0.f;
#pragma unroll
                for (int ni = 0; ni < 4; ++ni) {
#pragma unroll
                    for (int j = 0; j < 4; ++j) {
                        float p = exp2f(sc[mi][ni][j] - mrow[mi]);
                        sc[mi][ni][j] = p;
                        ps += p;
                    }
                    pk[mi][ni][0] = pack_bf2(sc[mi][ni][0], sc[mi][ni][1]);
                    pk[mi][ni][1] = pack_bf2(sc[mi][ni][2], sc[mi][ni][3]);
                }
                lrow[mi] += ps;
            }
            // ---- PV: PA frags by lane-shuffle, V from prefetched regs
#pragma unroll
            for (int kc = 0; kc < 2; ++kc) {
                union { int i[4]; bf16x8 v; } pa[2];
#pragma unroll
                for (int mi = 0; mi < 2; ++mi) {
                    int a0 = __shfl((int)pk[mi][2 * kc][0], s0, 64);
                    int b0 = __shfl((int)pk[mi][2 * kc + 1][0], s0, 64);
                    int a1 = __shfl((int)pk[mi][2 * kc][1], s0, 64);
                    int b1 = __shfl((int)pk[mi][2 * kc + 1][1], s0, 64);
                    int a2 = __shfl((int)pk[mi][2 * kc][0], s1, 64);
                    int b2 = __shfl((int)pk[mi][2 * kc + 1][0], s1, 64);
                    int a3 = __shfl((int)pk[mi][2 * kc][1], s1, 64);
                    int b3 = __shfl((int)pk[mi][2 * kc + 1][1], s1, 64);
                    pa[mi].i[0] = hi_ni ? b0 : a0;
                    pa[mi].i[1] = hi_ni ? b1 : a1;
                    pa[mi].i[2] = hi_ni ? b2 : a2;
                    pa[mi].i[3] = hi_ni ? b3 : a3;
                }
                __builtin_amdgcn_s_setprio(1);
#pragma unroll
                for (int n = 0; n < 8; ++n)
#pragma unroll
                    for (int mi = 0; mi < 2; ++mi)
                        o_acc[mi][n] = __builtin_amdgcn_mfma_f32_16x16x32_bf16(
                            pa[mi].v, vfr[kc][n], o_acc[mi][n], 0, 0, 0);
                __builtin_amdgcn_s_setprio(0);
            }
        }
        __builtin_amdgcn_s_barrier();
    }

    // ---- epilogue: reduce lrow partials across lanes, then normalize + store
    float invq[2];
#pragma unroll
    for (int mi = 0; mi < 2; ++mi) {
        float s = lrow[mi];
        s += __shfl_xor(s, 16, 64);
        s += __shfl_xor(s, 32, 64);
        invq[mi] = 1.0f / s;
    }
    short* aor = ao + ((long)(b * SEQ + qbase) * DIMSZ + h * HD);
#pragma unroll
    for (int mi = 0; mi < 2; ++mi)
#pragma unroll
        for (int j = 0; j < 4; ++j) {
            float ij = __shfl(invq[mi], (lane & 48) | (lg * 4 + j), 64);
#pragma unroll
            for (int n = 0; n < 8; ++n)
                aor[(mi * 16 + lg * 4 + j) * DIMSZ + n * 16 + lr] =
                    f2bf(o_acc[mi][n][j] * ij);
        }
}

// ---------------- launcher ----------------
extern "C" void kernel_launch(void* const* d_in, const int* in_sizes, int n_in,
                              void* d_out, int out_size, void* d_ws, size_t ws_size,
                              hipStream_t stream) {
    const float* x     = (const float*)d_in[0];
    // d_in[1] is the causal mask; semantics hardcoded (tril), not read.
    const float* W_qkv = (const float*)d_in[2];
    const float* b_qkv = (const float*)d_in[3];
    const float* W_out = (const float*)d_in[4];
    const float* b_out = (const float*)d_in[5];
    float* out = (float*)d_out;

    char* ws = (char*)d_ws;
    short* x_bf   = (short*)ws;                          // 16 MB
    short* wqkv_t = (short*)(ws + (size_t)16 * 1048576); // 24 MB
    short* wout_t = (short*)(ws + (size_t)40 * 1048576); //  8 MB
    short* q_buf  = (short*)(ws + (size_t)48 * 1048576); // 16 MB
    short* k_buf  = (short*)(ws + (size_t)64 * 1048576); // 16 MB
    short* vt_buf = (short*)(ws + (size_t)80 * 1048576); // 16 MB
    short* ao     = x_bf;  // x_bf dead after gemm1; reuse for attention output

    fused_prep<<<24576, 256, 0, stream>>>(x, x_bf, W_qkv, wqkv_t, W_out, wout_t);
    // gemm1: 4096x6144x2048, tiles 256x192 -> 16x32 = 512 blocks (2 full rounds)
    gemm8p<0, 256, 192, 4, 2><<<512, 512, 0, stream>>>(x_bf, wqkv_t, b_qkv, nullptr,
                                                       q_buf, k_buf, vt_buf, 32);
    attn_kernel<<<512, 256, 0, stream>>>(q_buf, k_buf, vt_buf, ao);
    // gemm2: 4096x2048x2048, tiles 128x256 -> 32x8 = 256 blocks (1 round)
    gemm8p<1, 128, 256, 2, 4><<<256, 512, 0, stream>>>(ao, wout_t, b_out, out,
                                                       nullptr, nullptr, nullptr, 8);
}